// Round 4
// baseline (272.785 us; speedup 1.0000x reference)
//
#include <hip/hip_runtime.h>
#include <hip/hip_bf16.h>
#include <math.h>
#include <stdint.h>

typedef unsigned short u16;
typedef __attribute__((ext_vector_type(8))) short bf16x8;
typedef __attribute__((ext_vector_type(4))) float f32x4;
typedef __attribute__((ext_vector_type(4))) unsigned short u16x4;

#define MFMA_BF16(A, B, C) __builtin_amdgcn_mfma_f32_16x16x32_bf16((A), (B), (C), 0, 0, 0)

__device__ __forceinline__ void async16(const void* g, const void* l) {
    __builtin_amdgcn_global_load_lds(
        (const __attribute__((address_space(1))) unsigned int*)(uintptr_t)g,
        (__attribute__((address_space(3))) unsigned int*)(uintptr_t)l, 16, 0, 0);
}

__device__ __forceinline__ u16 f2bf(float f) {
    unsigned u = __float_as_uint(f);
    u += 0x7fffu + ((u >> 16) & 1u);
    return (u16)(u >> 16);
}

__device__ __forceinline__ unsigned pack2(float a, float b) {
    __hip_bfloat162 h = __float22bfloat162_rn(float2{a, b});
    return *reinterpret_cast<unsigned*>(&h);
}

__device__ __forceinline__ float bf2f(u16 v) {
    unsigned u = ((unsigned)v) << 16;
    return __uint_as_float(u);
}

// ---------------------------------------------------------------------------
// Converters
// ---------------------------------------------------------------------------
__global__ __launch_bounds__(256) void cvt_x(const float* __restrict__ x,
                                             u16* __restrict__ xb) {
    int i = blockIdx.x * 256 + threadIdx.x;
    float4 v = ((const float4*)x)[i];
    u16x4 o = {f2bf(v.x), f2bf(v.y), f2bf(v.z), f2bf(v.w)};
    ((u16x4*)xb)[i] = o;
}

// All 4 weights fp32 [K=1024][N] -> bf16 [N][1024] in one launch.
__global__ __launch_bounds__(256) void cvt_w_all(
    const float* __restrict__ Wq, const float* __restrict__ Wks,
    const float* __restrict__ Wkl, const float* __restrict__ Wo,
    u16* __restrict__ wqt, u16* __restrict__ wkst,
    u16* __restrict__ wklt, u16* __restrict__ wot)
{
    __shared__ float tile[32][33];
    int x = blockIdx.x;
    const float* W; u16* Wt; int N, nb;
    if (x < 32)       { W = Wq;  Wt = wqt;  N = 1024; nb = x * 32; }
    else if (x < 96)  { W = Wks; Wt = wkst; N = 2048; nb = (x - 32) * 32; }
    else if (x < 160) { W = Wkl; Wt = wklt; N = 2048; nb = (x - 96) * 32; }
    else              { W = Wo;  Wt = wot;  N = 1024; nb = (x - 160) * 32; }
    int kb = blockIdx.y * 32;
    int t = threadIdx.x;
    int r = t >> 3, c4 = (t & 7) * 4;
    float4 v = *(const float4*)&W[(size_t)(kb + r) * N + nb + c4];
    tile[r][c4] = v.x; tile[r][c4 + 1] = v.y;
    tile[r][c4 + 2] = v.z; tile[r][c4 + 3] = v.w;
    __syncthreads();
    u16x4 o = {f2bf(tile[c4 + 0][r]), f2bf(tile[c4 + 1][r]),
               f2bf(tile[c4 + 2][r]), f2bf(tile[c4 + 3][r])};
    *(u16x4*)&Wt[(size_t)(nb + r) * 1024 + kb + c4] = o;
}

// ---------------------------------------------------------------------------
// Fused projection GEMM (XOR-swizzled LDS). Q output pre-scaled by
// 0.125*log2(e) so attention can use exp2 directly.
// ---------------------------------------------------------------------------
__global__ __launch_bounds__(256) void gemm_proj(
    const u16* __restrict__ A, const u16* __restrict__ wq,
    const u16* __restrict__ wks, const u16* __restrict__ wkl,
    u16* __restrict__ qd, u16* __restrict__ ksd, u16* __restrict__ vsd,
    u16* __restrict__ kld, u16* __restrict__ vld)
{
    __shared__ u16 Alds[128][32];
    __shared__ u16 Blds[128][32];
    const int cx = blockIdx.x;
    const u16* Bt; u16* d0; u16* d1; int colBase; float osc;
    if (cx < 8)       { Bt = wq;  colBase = cx * 128;        d0 = qd;  d1 = nullptr; osc = 0.18033688f; }
    else if (cx < 24) { Bt = wks; colBase = (cx - 8) * 128;  d0 = ksd; d1 = vsd; osc = 1.0f; }
    else              { Bt = wkl; colBase = (cx - 24) * 128; d0 = kld; d1 = vld; osc = 1.0f; }

    const int t = threadIdx.x;
    const int l = t & 63, w = t >> 6;
    const int wm = w & 1, wn = w >> 1;
    const int rowBase = blockIdx.y * 128;
    const int lc = l & 15, lr4 = l >> 4;

    f32x4 acc[4][4];
#pragma unroll
    for (int i = 0; i < 4; i++)
#pragma unroll
        for (int j = 0; j < 4; j++) acc[i][j] = (f32x4){0.f, 0.f, 0.f, 0.f};

    const int srow = w * 32 + (l >> 2);
    const int sc8  = (((l & 3) ^ ((l >> 2) & 3)) * 8);  // XOR-swizzled chunk
    const u16* Ag = A  + (size_t)(rowBase + srow) * 1024 + sc8;
    const u16* Bg = Bt + (size_t)(colBase + srow) * 1024 + sc8;
    const int sw = (lc & 3);  // read-side swizzle key (row & 3 == lc & 3)

    for (int kt = 0; kt < 32; ++kt) {
        __syncthreads();
        const int ko = kt * 32;
        async16(Ag + ko,         &Alds[w * 32][0]);
        async16(Ag + ko + 16384, &Alds[w * 32 + 16][0]);
        async16(Bg + ko,         &Blds[w * 32][0]);
        async16(Bg + ko + 16384, &Blds[w * 32 + 16][0]);
        __syncthreads();

        bf16x8 af[4], bf[4];
#pragma unroll
        for (int mt = 0; mt < 4; ++mt)
            af[mt] = *(const bf16x8*)&Alds[wm * 64 + mt * 16 + lc][(lr4 ^ sw) * 8];
#pragma unroll
        for (int nt = 0; nt < 4; ++nt)
            bf[nt] = *(const bf16x8*)&Blds[wn * 64 + nt * 16 + lc][(lr4 ^ sw) * 8];
#pragma unroll
        for (int mt = 0; mt < 4; ++mt)
#pragma unroll
            for (int nt = 0; nt < 4; ++nt)
                acc[mt][nt] = MFMA_BF16(af[mt], bf[nt], acc[mt][nt]);
    }

#pragma unroll
    for (int mt = 0; mt < 4; ++mt) {
#pragma unroll
        for (int nt = 0; nt < 4; ++nt) {
            const int gr0 = rowBase + wm * 64 + mt * 16 + lr4 * 4;
            const int gc0 = colBase + wn * 64 + nt * 16;
            const int head = gc0 >> 6;
            if (head < 16) {   // Q or K: head-major [B,16,L,64]
#pragma unroll
                for (int r = 0; r < 4; ++r) {
                    int gr = gr0 + r, b = gr >> 10, tok = gr & 1023;
                    d0[((size_t)(b * 16 + head) * 1024 + tok) * 64 +
                       ((gc0 & 63) + lc)] = f2bf(acc[mt][nt][r] * osc);
                }
            } else {           // V: transposed [B,16,64,L]
                int b = gr0 >> 10, tok = gr0 & 1023;
                int d = (gc0 & 63) + lc;
                u16x4 pv = {f2bf(acc[mt][nt][0]), f2bf(acc[mt][nt][1]),
                            f2bf(acc[mt][nt][2]), f2bf(acc[mt][nt][3])};
                *(u16x4*)&d1[((size_t)(b * 16 + head - 16) * 64 + d) * 1024 +
                             tok] = pv;
            }
        }
    }
}

// ---------------------------------------------------------------------------
// Output GEMM (XOR-swizzled LDS): fp32 C = attn_bf16 x Wo^T
// ---------------------------------------------------------------------------
__global__ __launch_bounds__(256) void gemm_out(
    const u16* __restrict__ A, const u16* __restrict__ Bt,
    float* __restrict__ dst)
{
    __shared__ u16 Alds[128][32];
    __shared__ u16 Blds[128][32];
    const int t = threadIdx.x;
    const int l = t & 63, w = t >> 6;
    const int wm = w & 1, wn = w >> 1;
    const int rowBase = blockIdx.y * 128, colBase = blockIdx.x * 128;
    const int lc = l & 15, lr4 = l >> 4;

    f32x4 acc[4][4];
#pragma unroll
    for (int i = 0; i < 4; i++)
#pragma unroll
        for (int j = 0; j < 4; j++) acc[i][j] = (f32x4){0.f, 0.f, 0.f, 0.f};

    const int srow = w * 32 + (l >> 2);
    const int sc8  = (((l & 3) ^ ((l >> 2) & 3)) * 8);
    const u16* Ag = A  + (size_t)(rowBase + srow) * 1024 + sc8;
    const u16* Bg = Bt + (size_t)(colBase + srow) * 1024 + sc8;
    const int sw = (lc & 3);

    for (int kt = 0; kt < 32; ++kt) {
        __syncthreads();
        const int ko = kt * 32;
        async16(Ag + ko,         &Alds[w * 32][0]);
        async16(Ag + ko + 16384, &Alds[w * 32 + 16][0]);
        async16(Bg + ko,         &Blds[w * 32][0]);
        async16(Bg + ko + 16384, &Blds[w * 32 + 16][0]);
        __syncthreads();

        bf16x8 af[4], bf[4];
#pragma unroll
        for (int mt = 0; mt < 4; ++mt)
            af[mt] = *(const bf16x8*)&Alds[wm * 64 + mt * 16 + lc][(lr4 ^ sw) * 8];
#pragma unroll
        for (int nt = 0; nt < 4; ++nt)
            bf[nt] = *(const bf16x8*)&Blds[wn * 64 + nt * 16 + lc][(lr4 ^ sw) * 8];
#pragma unroll
        for (int mt = 0; mt < 4; ++mt)
#pragma unroll
            for (int nt = 0; nt < 4; ++nt)
                acc[mt][nt] = MFMA_BF16(af[mt], bf[nt], acc[mt][nt]);
    }

#pragma unroll
    for (int mt = 0; mt < 4; ++mt)
#pragma unroll
        for (int nt = 0; nt < 4; ++nt) {
            const int gr0 = rowBase + wm * 64 + mt * 16 + lr4 * 4;
            const int gc0 = colBase + wn * 64 + nt * 16;
#pragma unroll
            for (int r = 0; r < 4; ++r)
                dst[(size_t)(gr0 + r) * 1024 + gc0 + lc] = acc[mt][nt][r];
        }
}

// ---------------------------------------------------------------------------
// Flash attention, transposed-MFMA (S^T, O^T), ONE branch per block.
// grid = (8 q-tiles, 16 heads, 8 = batch*2+branch); 4 blocks/CU.
// Q pre-scaled by 0.125*log2e. Fixed-max softmax. XOR-swizzled staging.
// Normalized branch output -> Os or Ol (bf16, token-major).
// ---------------------------------------------------------------------------
__global__ __launch_bounds__(256, 4) void attn_mfma(
    const u16* __restrict__ Q, const u16* __restrict__ Ksb,
    const u16* __restrict__ Vsb, const u16* __restrict__ Klb,
    const u16* __restrict__ Vlb, const float* __restrict__ decayf,
    u16* __restrict__ Os, u16* __restrict__ Ol)
{
    __shared__ u16 Kt[2][64][32];             // [d-half][krow][32 d] swizzled
    __shared__ u16 Vt[2][64][32];             // [krow-half][d][32 krow] swz
    __shared__ union {
        u16 q[2][128][32];                    // [d-half][qrow][32 d] swizzled
        u16 p[4][32][72];                     // per wave [qrow][krow(+8 pad)]
    } QP;

    const int t = threadIdx.x;
    const int l = t & 63, w = t >> 6;
    const int lc = l & 15, lr4 = l >> 4;
    const int qt = blockIdx.x, h = blockIdx.y;
    const int b = blockIdx.z >> 1, branch = blockIdx.z & 1;
    const size_t bh = (size_t)(b * 16 + h);
    const int qbase = qt * 128;
    const u16* Qg = Q + bh * (1024 * 64);
    const u16* Kg = (branch ? Klb : Ksb) + bh * (1024 * 64);
    const u16* Vg = (branch ? Vlb : Vsb) + bh * (64 * 1024);
    u16* outp = branch ? Ol : Os;

    const int sl   = l >> 2;                    // staging row within 16
    const int scs  = (((l & 3) ^ (sl & 3)) * 8);  // swizzled chunk offset
    const int sw   = (lc & 3);                  // read-side swizzle key

    // ---- stage Q (128 rows x 64 d) once ----
#pragma unroll
    for (int i = 0; i < 4; i++) {
        int id = w * 4 + i, kh = id >> 3, ch = id & 7;
        async16(Qg + (size_t)(qbase + ch * 16 + sl) * 64 + kh * 32 + scs,
                &QP.q[kh][ch * 16][0]);
    }
    __syncthreads();
    bf16x8 aQ[2][2];
#pragma unroll
    for (int qg = 0; qg < 2; ++qg)
#pragma unroll
        for (int kh = 0; kh < 2; ++kh)
            aQ[qg][kh] =
                *(const bf16x8*)&QP.q[kh][w * 32 + qg * 16 + lc][(lr4 ^ sw) * 8];

    const float C2 = (1.0f - decayf[0]) * 1.44269504f;
    const float qf = (float)(qbase + w * 32 + lc);

    float lrun[2] = {0.f, 0.f};
    f32x4 o[2][4];
#pragma unroll
    for (int qg = 0; qg < 2; ++qg)
#pragma unroll
        for (int dt = 0; dt < 4; ++dt) o[qg][dt] = (f32x4){0.f, 0.f, 0.f, 0.f};

    for (int kt = 0; kt < 16; ++kt) {
        __syncthreads();
#pragma unroll
        for (int i = 0; i < 4; i++) {
            int id = w * 4 + i;
            int kh = (id >> 2) & 1, ch = id & 3;
            if (id < 8)
                async16(Kg + (size_t)(kt * 64 + ch * 16 + sl) * 64 +
                            kh * 32 + scs,
                        &Kt[kh][ch * 16][0]);
            else
                async16(Vg + (size_t)(ch * 16 + sl) * 1024 + kt * 64 +
                            kh * 32 + scs,
                        &Vt[kh][ch * 16][0]);
        }
        __syncthreads();

        bf16x8 ak[4][2];
#pragma unroll
        for (int nt = 0; nt < 4; ++nt) {
            ak[nt][0] = *(const bf16x8*)&Kt[0][nt * 16 + lc][(lr4 ^ sw) * 8];
            ak[nt][1] = *(const bf16x8*)&Kt[1][nt * 16 + lc][(lr4 ^ sw) * 8];
        }

#pragma unroll
        for (int qg = 0; qg < 2; ++qg) {
            f32x4 s[4];
#pragma unroll
            for (int nt = 0; nt < 4; ++nt) {
                s[nt] = (f32x4){0.f, 0.f, 0.f, 0.f};
                s[nt] = MFMA_BF16(ak[nt][0], aQ[qg][0], s[nt]);
                s[nt] = MFMA_BF16(ak[nt][1], aQ[qg][1], s[nt]);
            }
            const float d0 = qf + (float)(qg * 16 - kt * 64 - lr4 * 4);
            float sum = 0.f;
#pragma unroll
            for (int nt = 0; nt < 4; ++nt) {
                float p[4];
#pragma unroll
                for (int r = 0; r < 4; ++r) {
                    float a = s[nt][r];
                    if (branch == 0)
                        a -= fabsf(d0 - (float)(nt * 16 + r)) * C2;
                    p[r] = exp2f(a);
                    sum += p[r];
                }
                uint2 w2 = {pack2(p[0], p[1]), pack2(p[2], p[3])};
                *(uint2*)&QP.p[w][qg * 16 + lc][nt * 16 + lr4 * 4] = w2;
            }
            lrun[qg] += sum;
        }

        bf16x8 pb[2][2];
#pragma unroll
        for (int qg = 0; qg < 2; ++qg)
#pragma unroll
            for (int c = 0; c < 2; ++c)
                pb[qg][c] = *(const bf16x8*)&QP.p[w][qg * 16 + lc]
                                                 [c * 32 + lr4 * 8];
#pragma unroll
        for (int dt = 0; dt < 4; ++dt) {
            bf16x8 v0 = *(const bf16x8*)&Vt[0][dt * 16 + lc][(lr4 ^ sw) * 8];
            bf16x8 v1 = *(const bf16x8*)&Vt[1][dt * 16 + lc][(lr4 ^ sw) * 8];
#pragma unroll
            for (int qg = 0; qg < 2; ++qg) {
                o[qg][dt] = MFMA_BF16(v0, pb[qg][0], o[qg][dt]);
                o[qg][dt] = MFMA_BF16(v1, pb[qg][1], o[qg][dt]);
            }
        }
    }

#pragma unroll
    for (int qg = 0; qg < 2; ++qg) {
        float s = lrun[qg];
        s += __shfl_xor(s, 16);
        s += __shfl_xor(s, 32);
        float inv = 1.0f / s;
        int qrow = qbase + w * 32 + qg * 16 + lc;
        u16* op = outp + ((size_t)(b * 1024) + qrow) * 1024 + h * 64;
#pragma unroll
        for (int dt = 0; dt < 4; ++dt) {
            uint2 w2 = {pack2(o[qg][dt][0] * inv, o[qg][dt][1] * inv),
                        pack2(o[qg][dt][2] * inv, o[qg][dt][3] * inv)};
            *(uint2*)&op[dt * 16 + lr4 * 4] = w2;
        }
    }
}

// ---------------------------------------------------------------------------
// Mix: attn = alpha*Os + (1-alpha)*Ol, elementwise bf16. 8 elems/thread.
// ---------------------------------------------------------------------------
__global__ __launch_bounds__(256) void mix_kernel(
    const u16* __restrict__ Os, const u16* __restrict__ Ol,
    const float* __restrict__ mixw, u16* __restrict__ dst)
{
    const float a = 1.0f / (1.0f + __expf(-mixw[0]));
    int i = blockIdx.x * 256 + threadIdx.x;
    uint4 s = ((const uint4*)Os)[i];
    uint4 l = ((const uint4*)Ol)[i];
    unsigned su[4] = {s.x, s.y, s.z, s.w};
    unsigned lu[4] = {l.x, l.y, l.z, l.w};
    unsigned ou[4];
#pragma unroll
    for (int k = 0; k < 4; ++k) {
        float s0 = bf2f((u16)su[k]), s1 = bf2f((u16)(su[k] >> 16));
        float l0 = bf2f((u16)lu[k]), l1 = bf2f((u16)(lu[k] >> 16));
        ou[k] = pack2(l0 + a * (s0 - l0), l1 + a * (s1 - l1));
    }
    ((uint4*)dst)[i] = make_uint4(ou[0], ou[1], ou[2], ou[3]);
}

// ---------------------------------------------------------------------------
extern "C" void kernel_launch(void* const* d_in, const int* in_sizes, int n_in,
                              void* d_out, int out_size, void* d_ws, size_t ws_size,
                              hipStream_t stream) {
    const float* x      = (const float*)d_in[0];
    const float* Wq     = (const float*)d_in[1];
    const float* Wkvs   = (const float*)d_in[2];
    const float* Wkvl   = (const float*)d_in[3];
    const float* Wo     = (const float*)d_in[4];
    const float* mixw   = (const float*)d_in[5];
    const float* decayf = (const float*)d_in[6];

    const size_t M1 = 1024 * 1024;
    u16* ws    = (u16*)d_ws;
    u16* xb    = ws;               // 4M  (reused as Os after gemm_proj)
    u16* wqt   = xb + 4 * M1;      // 1M  (wqt..wkvlt reused as Ol)
    u16* wkvst = wqt + 1 * M1;     // 2M
    u16* wkvlt = wkvst + 2 * M1;   // 2M
    u16* wot   = wkvlt + 2 * M1;   // 1M
    u16* qb    = wot + 1 * M1;     // 4M
    u16* ksb   = qb + 4 * M1;      // 4M
    u16* vsb   = ksb + 4 * M1;     // 4M  ([B,16,64,L])
    u16* klb   = vsb + 4 * M1;     // 4M
    u16* vlb   = klb + 4 * M1;     // 4M
    u16* attnb = vlb + 4 * M1;     // 4M
    u16* osb   = xb;               // alias: free after gemm_proj
    u16* olb   = wqt;              // alias: free after gemm_proj (4M spans wqt..wkvlt)

    cvt_x<<<4096, 256, 0, stream>>>(x, xb);
    cvt_w_all<<<dim3(192, 32), 256, 0, stream>>>(Wq, Wkvs, Wkvl, Wo,
                                                 wqt, wkvst, wkvlt, wot);
    gemm_proj<<<dim3(40, 32), 256, 0, stream>>>(xb, wqt, wkvst, wkvlt,
                                                qb, ksb, vsb, klb, vlb);
    attn_mfma<<<dim3(8, 16, 8), 256, 0, stream>>>(qb, ksb, vsb, klb, vlb,
                                                  decayf, osb, olb);
    mix_kernel<<<2048, 256, 0, stream>>>(osb, olb, mixw, attnb);
    gemm_out<<<dim3(8, 32), 256, 0, stream>>>(attnb, wot, (float*)d_out);
}

// Round 5
// 270.875 us; speedup vs baseline: 1.0071x; 1.0071x over previous
//
#include <hip/hip_runtime.h>
#include <hip/hip_bf16.h>
#include <math.h>
#include <stdint.h>

typedef unsigned short u16;
typedef __attribute__((ext_vector_type(8))) short bf16x8;
typedef __attribute__((ext_vector_type(4))) float f32x4;
typedef __attribute__((ext_vector_type(4))) unsigned short u16x4;

#define MFMA_BF16(A, B, C) __builtin_amdgcn_mfma_f32_16x16x32_bf16((A), (B), (C), 0, 0, 0)

__device__ __forceinline__ void async16(const void* g, const void* l) {
    __builtin_amdgcn_global_load_lds(
        (const __attribute__((address_space(1))) unsigned int*)(uintptr_t)g,
        (__attribute__((address_space(3))) unsigned int*)(uintptr_t)l, 16, 0, 0);
}

__device__ __forceinline__ u16 f2bf(float f) {
    unsigned u = __float_as_uint(f);
    u += 0x7fffu + ((u >> 16) & 1u);
    return (u16)(u >> 16);
}

__device__ __forceinline__ unsigned pack2(float a, float b) {
    __hip_bfloat162 h = __float22bfloat162_rn(float2{a, b});
    return *reinterpret_cast<unsigned*>(&h);
}

__device__ __forceinline__ float bf2f(u16 v) {
    unsigned u = ((unsigned)v) << 16;
    return __uint_as_float(u);
}

// ---------------------------------------------------------------------------
// Converters
// ---------------------------------------------------------------------------
__global__ __launch_bounds__(256) void cvt_x(const float* __restrict__ x,
                                             u16* __restrict__ xb) {
    int i = blockIdx.x * 256 + threadIdx.x;
    float4 v = ((const float4*)x)[i];
    u16x4 o = {f2bf(v.x), f2bf(v.y), f2bf(v.z), f2bf(v.w)};
    ((u16x4*)xb)[i] = o;
}

// All 4 weights fp32 [K=1024][N] -> bf16 [N][1024] in one launch.
__global__ __launch_bounds__(256) void cvt_w_all(
    const float* __restrict__ Wq, const float* __restrict__ Wks,
    const float* __restrict__ Wkl, const float* __restrict__ Wo,
    u16* __restrict__ wqt, u16* __restrict__ wkst,
    u16* __restrict__ wklt, u16* __restrict__ wot)
{
    __shared__ float tile[32][33];
    int x = blockIdx.x;
    const float* W; u16* Wt; int N, nb;
    if (x < 32)       { W = Wq;  Wt = wqt;  N = 1024; nb = x * 32; }
    else if (x < 96)  { W = Wks; Wt = wkst; N = 2048; nb = (x - 32) * 32; }
    else if (x < 160) { W = Wkl; Wt = wklt; N = 2048; nb = (x - 96) * 32; }
    else              { W = Wo;  Wt = wot;  N = 1024; nb = (x - 160) * 32; }
    int kb = blockIdx.y * 32;
    int t = threadIdx.x;
    int r = t >> 3, c4 = (t & 7) * 4;
    float4 v = *(const float4*)&W[(size_t)(kb + r) * N + nb + c4];
    tile[r][c4] = v.x; tile[r][c4 + 1] = v.y;
    tile[r][c4 + 2] = v.z; tile[r][c4 + 3] = v.w;
    __syncthreads();
    u16x4 o = {f2bf(tile[c4 + 0][r]), f2bf(tile[c4 + 1][r]),
               f2bf(tile[c4 + 2][r]), f2bf(tile[c4 + 3][r])};
    *(u16x4*)&Wt[(size_t)(nb + r) * 1024 + kb + c4] = o;
}

// ---------------------------------------------------------------------------
// Fused projection GEMM. Q output pre-scaled by 0.125*log2(e).
// ---------------------------------------------------------------------------
__global__ __launch_bounds__(256) void gemm_proj(
    const u16* __restrict__ A, const u16* __restrict__ wq,
    const u16* __restrict__ wks, const u16* __restrict__ wkl,
    u16* __restrict__ qd, u16* __restrict__ ksd, u16* __restrict__ vsd,
    u16* __restrict__ kld, u16* __restrict__ vld)
{
    __shared__ u16 Alds[128][32];
    __shared__ u16 Blds[128][32];
    const int cx = blockIdx.x;
    const u16* Bt; u16* d0; u16* d1; int colBase; float osc;
    if (cx < 8)       { Bt = wq;  colBase = cx * 128;        d0 = qd;  d1 = nullptr; osc = 0.18033688f; }
    else if (cx < 24) { Bt = wks; colBase = (cx - 8) * 128;  d0 = ksd; d1 = vsd; osc = 1.0f; }
    else              { Bt = wkl; colBase = (cx - 24) * 128; d0 = kld; d1 = vld; osc = 1.0f; }

    const int t = threadIdx.x;
    const int l = t & 63, w = t >> 6;
    const int wm = w & 1, wn = w >> 1;
    const int rowBase = blockIdx.y * 128;
    const int lc = l & 15, lr4 = l >> 4;

    f32x4 acc[4][4];
#pragma unroll
    for (int i = 0; i < 4; i++)
#pragma unroll
        for (int j = 0; j < 4; j++) acc[i][j] = (f32x4){0.f, 0.f, 0.f, 0.f};

    const int srow = w * 32 + (l >> 2);
    const int sc8  = (((l & 3) ^ ((l >> 2) & 3)) * 8);
    const u16* Ag = A  + (size_t)(rowBase + srow) * 1024 + sc8;
    const u16* Bg = Bt + (size_t)(colBase + srow) * 1024 + sc8;
    const int sw = (lc & 3);

    for (int kt = 0; kt < 32; ++kt) {
        __syncthreads();
        const int ko = kt * 32;
        async16(Ag + ko,         &Alds[w * 32][0]);
        async16(Ag + ko + 16384, &Alds[w * 32 + 16][0]);
        async16(Bg + ko,         &Blds[w * 32][0]);
        async16(Bg + ko + 16384, &Blds[w * 32 + 16][0]);
        __syncthreads();

        bf16x8 af[4], bf[4];
#pragma unroll
        for (int mt = 0; mt < 4; ++mt)
            af[mt] = *(const bf16x8*)&Alds[wm * 64 + mt * 16 + lc][(lr4 ^ sw) * 8];
#pragma unroll
        for (int nt = 0; nt < 4; ++nt)
            bf[nt] = *(const bf16x8*)&Blds[wn * 64 + nt * 16 + lc][(lr4 ^ sw) * 8];
#pragma unroll
        for (int mt = 0; mt < 4; ++mt)
#pragma unroll
            for (int nt = 0; nt < 4; ++nt)
                acc[mt][nt] = MFMA_BF16(af[mt], bf[nt], acc[mt][nt]);
    }

#pragma unroll
    for (int mt = 0; mt < 4; ++mt) {
#pragma unroll
        for (int nt = 0; nt < 4; ++nt) {
            const int gr0 = rowBase + wm * 64 + mt * 16 + lr4 * 4;
            const int gc0 = colBase + wn * 64 + nt * 16;
            const int head = gc0 >> 6;
            if (head < 16) {   // Q or K: head-major [B,16,L,64]
#pragma unroll
                for (int r = 0; r < 4; ++r) {
                    int gr = gr0 + r, b = gr >> 10, tok = gr & 1023;
                    d0[((size_t)(b * 16 + head) * 1024 + tok) * 64 +
                       ((gc0 & 63) + lc)] = f2bf(acc[mt][nt][r] * osc);
                }
            } else {           // V: transposed [B,16,64,L]
                int b = gr0 >> 10, tok = gr0 & 1023;
                int d = (gc0 & 63) + lc;
                u16x4 pv = {f2bf(acc[mt][nt][0]), f2bf(acc[mt][nt][1]),
                            f2bf(acc[mt][nt][2]), f2bf(acc[mt][nt][3])};
                *(u16x4*)&d1[((size_t)(b * 16 + head - 16) * 64 + d) * 1024 +
                             tok] = pv;
            }
        }
    }
}

// ---------------------------------------------------------------------------
// Output GEMM: fp32 C = attn_bf16 x Wo^T
// ---------------------------------------------------------------------------
__global__ __launch_bounds__(256) void gemm_out(
    const u16* __restrict__ A, const u16* __restrict__ Bt,
    float* __restrict__ dst)
{
    __shared__ u16 Alds[128][32];
    __shared__ u16 Blds[128][32];
    const int t = threadIdx.x;
    const int l = t & 63, w = t >> 6;
    const int wm = w & 1, wn = w >> 1;
    const int rowBase = blockIdx.y * 128, colBase = blockIdx.x * 128;
    const int lc = l & 15, lr4 = l >> 4;

    f32x4 acc[4][4];
#pragma unroll
    for (int i = 0; i < 4; i++)
#pragma unroll
        for (int j = 0; j < 4; j++) acc[i][j] = (f32x4){0.f, 0.f, 0.f, 0.f};

    const int srow = w * 32 + (l >> 2);
    const int sc8  = (((l & 3) ^ ((l >> 2) & 3)) * 8);
    const u16* Ag = A  + (size_t)(rowBase + srow) * 1024 + sc8;
    const u16* Bg = Bt + (size_t)(colBase + srow) * 1024 + sc8;
    const int sw = (lc & 3);

    for (int kt = 0; kt < 32; ++kt) {
        __syncthreads();
        const int ko = kt * 32;
        async16(Ag + ko,         &Alds[w * 32][0]);
        async16(Ag + ko + 16384, &Alds[w * 32 + 16][0]);
        async16(Bg + ko,         &Blds[w * 32][0]);
        async16(Bg + ko + 16384, &Blds[w * 32 + 16][0]);
        __syncthreads();

        bf16x8 af[4], bf[4];
#pragma unroll
        for (int mt = 0; mt < 4; ++mt)
            af[mt] = *(const bf16x8*)&Alds[wm * 64 + mt * 16 + lc][(lr4 ^ sw) * 8];
#pragma unroll
        for (int nt = 0; nt < 4; ++nt)
            bf[nt] = *(const bf16x8*)&Blds[wn * 64 + nt * 16 + lc][(lr4 ^ sw) * 8];
#pragma unroll
        for (int mt = 0; mt < 4; ++mt)
#pragma unroll
            for (int nt = 0; nt < 4; ++nt)
                acc[mt][nt] = MFMA_BF16(af[mt], bf[nt], acc[mt][nt]);
    }

#pragma unroll
    for (int mt = 0; mt < 4; ++mt)
#pragma unroll
        for (int nt = 0; nt < 4; ++nt) {
            const int gr0 = rowBase + wm * 64 + mt * 16 + lr4 * 4;
            const int gc0 = colBase + wn * 64 + nt * 16;
#pragma unroll
            for (int r = 0; r < 4; ++r)
                dst[(size_t)(gr0 + r) * 1024 + gc0 + lc] = acc[mt][nt][r];
        }
}

// ---------------------------------------------------------------------------
// Flash attention, transposed-MFMA (S^T, O^T), one branch per block,
// K/V DOUBLE-BUFFERED with prefetch; ONE barrier per k-iteration.
// grid = (16 heads, 8 q-tiles, 8 = batch*2+branch)  [h fastest -> all 8
// q-tiles of one (h,b,branch) share an XCD for K/V L2 locality].
// Q fragments loaded directly from global (no LDS staging).
// ---------------------------------------------------------------------------
__global__ __launch_bounds__(256, 3) void attn_mfma(
    const u16* __restrict__ Q, const u16* __restrict__ Ksb,
    const u16* __restrict__ Vsb, const u16* __restrict__ Klb,
    const u16* __restrict__ Vlb, const float* __restrict__ decayf,
    u16* __restrict__ Os, u16* __restrict__ Ol)
{
    __shared__ __align__(16) u16 Kt[2][2][64][32];  // [buf][d-half][krow][32d]
    __shared__ __align__(16) u16 Vt[2][2][64][32];  // [buf][k-half][d][32krow]
    __shared__ __align__(16) u16 Ps[4][32][72];     // per wave [qrow][krow+pad]

    const int t = threadIdx.x;
    const int l = t & 63, w = t >> 6;
    const int lc = l & 15, lr4 = l >> 4;
    const int h = blockIdx.x, qt = blockIdx.y;
    const int b = blockIdx.z >> 1, branch = blockIdx.z & 1;
    const size_t bh = (size_t)(b * 16 + h);
    const int qbase = qt * 128;
    const u16* Qg = Q + bh * (1024 * 64);
    const u16* Kg = (branch ? Klb : Ksb) + bh * (1024 * 64);
    const u16* Vg = (branch ? Vlb : Vsb) + bh * (64 * 1024);
    u16* outp = branch ? Ol : Os;

    const int sl = l >> 2;          // staging row within 16
    const int sc = (l & 3) * 8;     // k-element chunk offset

    // ---- Q B-operand fragments straight from global (coalesced 16B) ----
    bf16x8 aQ[2][2];
#pragma unroll
    for (int qg = 0; qg < 2; ++qg)
#pragma unroll
        for (int kh = 0; kh < 2; ++kh)
            aQ[qg][kh] = *(const bf16x8*)&Qg[
                (size_t)(qbase + w * 32 + qg * 16 + lc) * 64 + kh * 32 + lr4 * 8];

    // ---- stage K/V tile kt into buffer buf (4 async16 per wave) ----
    auto stage = [&](int kt, int buf) {
#pragma unroll
        for (int i = 0; i < 4; i++) {
            int id = w * 4 + i;
            int kh = (id >> 2) & 1, ch = id & 3;
            if (id < 8)
                async16(Kg + (size_t)(kt * 64 + ch * 16 + sl) * 64 + kh * 32 + sc,
                        &Kt[buf][kh][ch * 16][0]);
            else
                async16(Vg + (size_t)(ch * 16 + sl) * 1024 + kt * 64 + kh * 32 + sc,
                        &Vt[buf][kh][ch * 16][0]);
        }
    };

    stage(0, 0);
    __syncthreads();   // drains Q loads + buf0 staging

    const float C2 = (1.0f - decayf[0]) * 1.44269504f;
    const float qf = (float)(qbase + w * 32 + lc);

    float lrun[2] = {0.f, 0.f};
    f32x4 o[2][4];
#pragma unroll
    for (int qg = 0; qg < 2; ++qg)
#pragma unroll
        for (int dt = 0; dt < 4; ++dt) o[qg][dt] = (f32x4){0.f, 0.f, 0.f, 0.f};

    for (int kt = 0; kt < 16; ++kt) {
        const int cur = kt & 1;
        // prefetch next tile into the other buffer; its vmcnt drain happens
        // at the END-of-iter barrier -> latency covered by this iter's math
        if (kt < 15) stage(kt + 1, cur ^ 1);

        bf16x8 ak[4][2];
#pragma unroll
        for (int nt = 0; nt < 4; ++nt) {
            ak[nt][0] = *(const bf16x8*)&Kt[cur][0][nt * 16 + lc][lr4 * 8];
            ak[nt][1] = *(const bf16x8*)&Kt[cur][1][nt * 16 + lc][lr4 * 8];
        }

#pragma unroll
        for (int qg = 0; qg < 2; ++qg) {
            f32x4 s[4];
#pragma unroll
            for (int nt = 0; nt < 4; ++nt) {
                s[nt] = (f32x4){0.f, 0.f, 0.f, 0.f};
                s[nt] = MFMA_BF16(ak[nt][0], aQ[qg][0], s[nt]);
                s[nt] = MFMA_BF16(ak[nt][1], aQ[qg][1], s[nt]);
            }
            const float d0 = qf + (float)(qg * 16 - kt * 64 - lr4 * 4);
            float sum = 0.f;
#pragma unroll
            for (int nt = 0; nt < 4; ++nt) {
                float p[4];
#pragma unroll
                for (int r = 0; r < 4; ++r) {
                    float a = s[nt][r];
                    if (branch == 0)
                        a -= fabsf(d0 - (float)(nt * 16 + r)) * C2;
                    p[r] = exp2f(a);
                    sum += p[r];
                }
                uint2 w2 = {pack2(p[0], p[1]), pack2(p[2], p[3])};
                *(uint2*)&Ps[w][qg * 16 + lc][nt * 16 + lr4 * 4] = w2;
            }
            lrun[qg] += sum;
        }

        // O^T += V^T P^T   (Ps is wave-private; same-wave lgkm ordering only)
        bf16x8 pb[2][2];
#pragma unroll
        for (int qg = 0; qg < 2; ++qg)
#pragma unroll
            for (int c = 0; c < 2; ++c)
                pb[qg][c] = *(const bf16x8*)&Ps[w][qg * 16 + lc][c * 32 + lr4 * 8];
#pragma unroll
        for (int dt = 0; dt < 4; ++dt) {
            bf16x8 v0 = *(const bf16x8*)&Vt[cur][0][dt * 16 + lc][lr4 * 8];
            bf16x8 v1 = *(const bf16x8*)&Vt[cur][1][dt * 16 + lc][lr4 * 8];
#pragma unroll
            for (int qg = 0; qg < 2; ++qg) {
                o[qg][dt] = MFMA_BF16(v0, pb[qg][0], o[qg][dt]);
                o[qg][dt] = MFMA_BF16(v1, pb[qg][1], o[qg][dt]);
            }
        }

        // one barrier: (a) prefetch vmcnt drained -> next buf ready;
        // (b) all waves done reading cur -> safe to overwrite next iter+1
        __syncthreads();
    }

#pragma unroll
    for (int qg = 0; qg < 2; ++qg) {
        float s = lrun[qg];
        s += __shfl_xor(s, 16);
        s += __shfl_xor(s, 32);
        float inv = 1.0f / s;
        int qrow = qbase + w * 32 + qg * 16 + lc;
        u16* op = outp + ((size_t)(b * 1024) + qrow) * 1024 + h * 64;
#pragma unroll
        for (int dt = 0; dt < 4; ++dt) {
            uint2 w2 = {pack2(o[qg][dt][0] * inv, o[qg][dt][1] * inv),
                        pack2(o[qg][dt][2] * inv, o[qg][dt][3] * inv)};
            *(uint2*)&op[dt * 16 + lr4 * 4] = w2;
        }
    }
}

// ---------------------------------------------------------------------------
// Mix: attn = alpha*Os + (1-alpha)*Ol, elementwise bf16. 8 elems/thread.
// ---------------------------------------------------------------------------
__global__ __launch_bounds__(256) void mix_kernel(
    const u16* __restrict__ Os, const u16* __restrict__ Ol,
    const float* __restrict__ mixw, u16* __restrict__ dst)
{
    const float a = 1.0f / (1.0f + __expf(-mixw[0]));
    int i = blockIdx.x * 256 + threadIdx.x;
    uint4 s = ((const uint4*)Os)[i];
    uint4 l = ((const uint4*)Ol)[i];
    unsigned su[4] = {s.x, s.y, s.z, s.w};
    unsigned lu[4] = {l.x, l.y, l.z, l.w};
    unsigned ou[4];
#pragma unroll
    for (int k = 0; k < 4; ++k) {
        float s0 = bf2f((u16)su[k]), s1 = bf2f((u16)(su[k] >> 16));
        float l0 = bf2f((u16)lu[k]), l1 = bf2f((u16)(lu[k] >> 16));
        ou[k] = pack2(l0 + a * (s0 - l0), l1 + a * (s1 - l1));
    }
    ((uint4*)dst)[i] = make_uint4(ou[0], ou[1], ou[2], ou[3]);
}

// ---------------------------------------------------------------------------
extern "C" void kernel_launch(void* const* d_in, const int* in_sizes, int n_in,
                              void* d_out, int out_size, void* d_ws, size_t ws_size,
                              hipStream_t stream) {
    const float* x      = (const float*)d_in[0];
    const float* Wq     = (const float*)d_in[1];
    const float* Wkvs   = (const float*)d_in[2];
    const float* Wkvl   = (const float*)d_in[3];
    const float* Wo     = (const float*)d_in[4];
    const float* mixw   = (const float*)d_in[5];
    const float* decayf = (const float*)d_in[6];

    const size_t M1 = 1024 * 1024;
    u16* ws    = (u16*)d_ws;
    u16* xb    = ws;               // 4M  (reused as Os after gemm_proj)
    u16* wqt   = xb + 4 * M1;      // 1M  (wqt..wkvlt reused as Ol)
    u16* wkvst = wqt + 1 * M1;     // 2M
    u16* wkvlt = wkvst + 2 * M1;   // 2M
    u16* wot   = wkvlt + 2 * M1;   // 1M
    u16* qb    = wot + 1 * M1;     // 4M
    u16* ksb   = qb + 4 * M1;      // 4M
    u16* vsb   = ksb + 4 * M1;     // 4M  ([B,16,64,L])
    u16* klb   = vsb + 4 * M1;     // 4M
    u16* vlb   = klb + 4 * M1;     // 4M
    u16* attnb = vlb + 4 * M1;     // 4M
    u16* osb   = xb;               // alias: free after gemm_proj
    u16* olb   = wqt;              // alias: free after gemm_proj

    cvt_x<<<4096, 256, 0, stream>>>(x, xb);
    cvt_w_all<<<dim3(192, 32), 256, 0, stream>>>(Wq, Wkvs, Wkvl, Wo,
                                                 wqt, wkvst, wkvlt, wot);
    gemm_proj<<<dim3(40, 32), 256, 0, stream>>>(xb, wqt, wkvst, wkvlt,
                                                qb, ksb, vsb, klb, vlb);
    attn_mfma<<<dim3(16, 8, 8), 256, 0, stream>>>(qb, ksb, vsb, klb, vlb,
                                                  decayf, osb, olb);
    mix_kernel<<<2048, 256, 0, stream>>>(osb, olb, mixw, attnb);
    gemm_out<<<dim3(8, 32), 256, 0, stream>>>(attnb, wot, (float*)d_out);
}

// Round 6
// 238.609 us; speedup vs baseline: 1.1432x; 1.1352x over previous
//
#include <hip/hip_runtime.h>
#include <hip/hip_bf16.h>
#include <math.h>
#include <stdint.h>

typedef unsigned short u16;
typedef __attribute__((ext_vector_type(8))) short bf16x8;
typedef __attribute__((ext_vector_type(4))) float f32x4;
typedef __attribute__((ext_vector_type(4))) unsigned short u16x4;

#define MFMA_BF16(A, B, C) __builtin_amdgcn_mfma_f32_16x16x32_bf16((A), (B), (C), 0, 0, 0)

__device__ __forceinline__ void async16(const void* g, const void* l) {
    __builtin_amdgcn_global_load_lds(
        (const __attribute__((address_space(1))) unsigned int*)(uintptr_t)g,
        (__attribute__((address_space(3))) unsigned int*)(uintptr_t)l, 16, 0, 0);
}

__device__ __forceinline__ u16 f2bf(float f) {
    unsigned u = __float_as_uint(f);
    u += 0x7fffu + ((u >> 16) & 1u);
    return (u16)(u >> 16);
}

__device__ __forceinline__ unsigned pack2(float a, float b) {
    __hip_bfloat162 h = __float22bfloat162_rn(float2{a, b});
    return *reinterpret_cast<unsigned*>(&h);
}

__device__ __forceinline__ float bf2f(u16 v) {
    unsigned u = ((unsigned)v) << 16;
    return __uint_as_float(u);
}

// ---------------------------------------------------------------------------
// Converters
// ---------------------------------------------------------------------------
__global__ __launch_bounds__(256) void cvt_x(const float* __restrict__ x,
                                             u16* __restrict__ xb) {
    int i = blockIdx.x * 256 + threadIdx.x;
    float4 v = ((const float4*)x)[i];
    u16x4 o = {f2bf(v.x), f2bf(v.y), f2bf(v.z), f2bf(v.w)};
    ((u16x4*)xb)[i] = o;
}

// All 4 weights fp32 [K=1024][N] -> bf16 [N][1024] in one launch.
__global__ __launch_bounds__(256) void cvt_w_all(
    const float* __restrict__ Wq, const float* __restrict__ Wks,
    const float* __restrict__ Wkl, const float* __restrict__ Wo,
    u16* __restrict__ wqt, u16* __restrict__ wkst,
    u16* __restrict__ wklt, u16* __restrict__ wot)
{
    __shared__ float tile[32][33];
    int x = blockIdx.x;
    const float* W; u16* Wt; int N, nb;
    if (x < 32)       { W = Wq;  Wt = wqt;  N = 1024; nb = x * 32; }
    else if (x < 96)  { W = Wks; Wt = wkst; N = 2048; nb = (x - 32) * 32; }
    else if (x < 160) { W = Wkl; Wt = wklt; N = 2048; nb = (x - 96) * 32; }
    else              { W = Wo;  Wt = wot;  N = 1024; nb = (x - 160) * 32; }
    int kb = blockIdx.y * 32;
    int t = threadIdx.x;
    int r = t >> 3, c4 = (t & 7) * 4;
    float4 v = *(const float4*)&W[(size_t)(kb + r) * N + nb + c4];
    tile[r][c4] = v.x; tile[r][c4 + 1] = v.y;
    tile[r][c4 + 2] = v.z; tile[r][c4 + 3] = v.w;
    __syncthreads();
    u16x4 o = {f2bf(tile[c4 + 0][r]), f2bf(tile[c4 + 1][r]),
               f2bf(tile[c4 + 2][r]), f2bf(tile[c4 + 3][r])};
    *(u16x4*)&Wt[(size_t)(nb + r) * 1024 + kb + c4] = o;
}

// ---------------------------------------------------------------------------
// Fused projection GEMM. Q pre-scaled by 0.125*log2(e).
// K-type blocks (Q, K cols) compute C^T (A=W, B=x) -> u16x4 head-major
// stores. V-type blocks compute C -> u16x4 transposed [B,16,64,L] stores.
// ---------------------------------------------------------------------------
__global__ __launch_bounds__(256) void gemm_proj(
    const u16* __restrict__ A, const u16* __restrict__ wq,
    const u16* __restrict__ wks, const u16* __restrict__ wkl,
    u16* __restrict__ qd, u16* __restrict__ ksd, u16* __restrict__ vsd,
    u16* __restrict__ kld, u16* __restrict__ vld)
{
    __shared__ u16 Alds[128][32];   // x rows (tokens)
    __shared__ u16 Blds[128][32];   // W rows (features)
    const int cx = blockIdx.x;
    const u16* Bt; u16* dK; u16* dV; int colBase; float osc = 1.0f;
    bool ktype;
    if (cx < 8)       { Bt = wq;  colBase = cx * 128;        dK = qd;  dV = nullptr;
                        osc = 0.18033688f; ktype = true; }
    else if (cx < 24) { Bt = wks; colBase = (cx - 8) * 128;  dK = ksd; dV = vsd;
                        ktype = (cx < 16); }
    else              { Bt = wkl; colBase = (cx - 24) * 128; dK = kld; dV = vld;
                        ktype = (cx < 32); }

    const int t = threadIdx.x;
    const int l = t & 63, w = t >> 6;
    const int wm = w & 1, wn = w >> 1;
    const int rowBase = blockIdx.y * 128;
    const int lc = l & 15, lr4 = l >> 4;

    f32x4 acc[4][4];
#pragma unroll
    for (int i = 0; i < 4; i++)
#pragma unroll
        for (int j = 0; j < 4; j++) acc[i][j] = (f32x4){0.f, 0.f, 0.f, 0.f};

    const int srow = w * 32 + (l >> 2);
    const int sc8  = (((l & 3) ^ ((l >> 2) & 3)) * 8);
    const u16* Ag = A  + (size_t)(rowBase + srow) * 1024 + sc8;
    const u16* Bg = Bt + (size_t)(colBase + srow) * 1024 + sc8;
    const int sw = (lc & 3);

    // m-index operand / n-index operand (swapped for ktype -> C^T)
    const u16 (*Lm)[32] = ktype ? Blds : Alds;
    const u16 (*Ln)[32] = ktype ? Alds : Blds;

    for (int kt = 0; kt < 32; ++kt) {
        __syncthreads();
        const int ko = kt * 32;
        async16(Ag + ko,         &Alds[w * 32][0]);
        async16(Ag + ko + 16384, &Alds[w * 32 + 16][0]);
        async16(Bg + ko,         &Blds[w * 32][0]);
        async16(Bg + ko + 16384, &Blds[w * 32 + 16][0]);
        __syncthreads();

        bf16x8 af[4], bf[4];
#pragma unroll
        for (int mt = 0; mt < 4; ++mt)
            af[mt] = *(const bf16x8*)&Lm[wm * 64 + mt * 16 + lc][(lr4 ^ sw) * 8];
#pragma unroll
        for (int nt = 0; nt < 4; ++nt)
            bf[nt] = *(const bf16x8*)&Ln[wn * 64 + nt * 16 + lc][(lr4 ^ sw) * 8];
#pragma unroll
        for (int mt = 0; mt < 4; ++mt)
#pragma unroll
            for (int nt = 0; nt < 4; ++nt)
                acc[mt][nt] = MFMA_BF16(af[mt], bf[nt], acc[mt][nt]);
    }

    if (ktype) {
        // C^T: m = features, n = tokens. Lane holds 4 consecutive d.
#pragma unroll
        for (int mt = 0; mt < 4; ++mt)
#pragma unroll
            for (int nt = 0; nt < 4; ++nt) {
                int f   = colBase + wm * 64 + mt * 16 + lr4 * 4;
                int tok = rowBase + wn * 64 + nt * 16 + lc;
                int b = tok >> 10, tk = tok & 1023;
                int head = (f >> 6) & 15, d = f & 63;
                u16x4 pv = {f2bf(acc[mt][nt][0] * osc), f2bf(acc[mt][nt][1] * osc),
                            f2bf(acc[mt][nt][2] * osc), f2bf(acc[mt][nt][3] * osc)};
                *(u16x4*)&dK[((size_t)(b * 16 + head) * 1024 + tk) * 64 + d] = pv;
            }
    } else {
        // C: m = tokens, n = features. Transposed V store [B,16,64,L].
#pragma unroll
        for (int mt = 0; mt < 4; ++mt)
#pragma unroll
            for (int nt = 0; nt < 4; ++nt) {
                int gr0 = rowBase + wm * 64 + mt * 16 + lr4 * 4;
                int gc0 = colBase + wn * 64 + nt * 16;
                int head = gc0 >> 6;            // 16..31
                int b = gr0 >> 10, tok = gr0 & 1023;
                int d = (gc0 & 63) + lc;
                u16x4 pv = {f2bf(acc[mt][nt][0]), f2bf(acc[mt][nt][1]),
                            f2bf(acc[mt][nt][2]), f2bf(acc[mt][nt][3])};
                *(u16x4*)&dV[((size_t)(b * 16 + head - 16) * 64 + d) * 1024 +
                             tok] = pv;
            }
    }
}

// ---------------------------------------------------------------------------
// Output GEMM: fp32 C = attn_bf16 x Wo^T, computed as C^T (A=Wo, B=attn).
// 64-token x 128-feature tiles -> 512 blocks (2/CU). float4 stores.
// ---------------------------------------------------------------------------
__global__ __launch_bounds__(256) void gemm_out(
    const u16* __restrict__ Aattn, const u16* __restrict__ Bwot,
    float* __restrict__ dst)
{
    __shared__ u16 Alds[64][32];    // tokens x k
    __shared__ u16 Blds[128][32];   // features x k
    const int t = threadIdx.x;
    const int l = t & 63, w = t >> 6;
    const int wm = w & 1, wn = w >> 1;          // wm: feature half, wn: token half
    const int rowBase = blockIdx.y * 64;        // tokens
    const int colBase = blockIdx.x * 128;       // features
    const int lc = l & 15, lr4 = l >> 4;

    f32x4 acc[4][2];
#pragma unroll
    for (int i = 0; i < 4; i++)
#pragma unroll
        for (int j = 0; j < 2; j++) acc[i][j] = (f32x4){0.f, 0.f, 0.f, 0.f};

    const int sl  = l >> 2;
    const int sc8 = (((l & 3) ^ (sl & 3)) * 8);
    const u16* Ag = Aattn + (size_t)(rowBase + w * 16 + sl) * 1024 + sc8;
    const u16* Bg = Bwot  + (size_t)(colBase + w * 32 + sl) * 1024 + sc8;
    const int sw = (lc & 3);

    for (int kt = 0; kt < 32; ++kt) {
        __syncthreads();
        const int ko = kt * 32;
        async16(Ag + ko,         &Alds[w * 16][0]);
        async16(Bg + ko,         &Blds[w * 32][0]);
        async16(Bg + ko + 16384, &Blds[w * 32 + 16][0]);
        __syncthreads();

        bf16x8 af[4], bf[2];
#pragma unroll
        for (int mt = 0; mt < 4; ++mt)
            af[mt] = *(const bf16x8*)&Blds[wm * 64 + mt * 16 + lc][(lr4 ^ sw) * 8];
#pragma unroll
        for (int nt = 0; nt < 2; ++nt)
            bf[nt] = *(const bf16x8*)&Alds[wn * 32 + nt * 16 + lc][(lr4 ^ sw) * 8];
#pragma unroll
        for (int mt = 0; mt < 4; ++mt)
#pragma unroll
            for (int nt = 0; nt < 2; ++nt)
                acc[mt][nt] = MFMA_BF16(af[mt], bf[nt], acc[mt][nt]);
    }

#pragma unroll
    for (int mt = 0; mt < 4; ++mt)
#pragma unroll
        for (int nt = 0; nt < 2; ++nt) {
            int f   = colBase + wm * 64 + mt * 16 + lr4 * 4;
            int tok = rowBase + wn * 32 + nt * 16 + lc;
            float4 v = {acc[mt][nt][0], acc[mt][nt][1],
                        acc[mt][nt][2], acc[mt][nt][3]};
            *(float4*)&dst[(size_t)tok * 1024 + f] = v;
        }
}

// ---------------------------------------------------------------------------
// Flash attention, transposed-MFMA (S^T, O^T), one branch per block,
// K/V double-buffered prefetch, one barrier/iter. Raw v_exp_f32.
// Branch 0 skips k-tiles with |q-k| > ~450 (decay weight < 2^-32).
// ---------------------------------------------------------------------------
__global__ __launch_bounds__(256, 3) void attn_mfma(
    const u16* __restrict__ Q, const u16* __restrict__ Ksb,
    const u16* __restrict__ Vsb, const u16* __restrict__ Klb,
    const u16* __restrict__ Vlb, const float* __restrict__ decayf,
    u16* __restrict__ Os, u16* __restrict__ Ol)
{
    __shared__ __align__(16) u16 Kt[2][2][64][32];  // [buf][d-half][krow][32d]
    __shared__ __align__(16) u16 Vt[2][2][64][32];  // [buf][k-half][d][32krow]
    __shared__ __align__(16) u16 Ps[4][32][72];     // per wave [qrow][krow+pad]

    const int t = threadIdx.x;
    const int l = t & 63, w = t >> 6;
    const int lc = l & 15, lr4 = l >> 4;
    const int h = blockIdx.x, qt = blockIdx.y;
    const int b = blockIdx.z >> 1, branch = blockIdx.z & 1;
    const size_t bh = (size_t)(b * 16 + h);
    const int qbase = qt * 128;
    const u16* Qg = Q + bh * (1024 * 64);
    const u16* Kg = (branch ? Klb : Ksb) + bh * (1024 * 64);
    const u16* Vg = (branch ? Vlb : Vsb) + bh * (64 * 1024);
    u16* outp = branch ? Ol : Os;

    const int sl = l >> 2;
    const int sc = (l & 3) * 8;

    // branch-0 range: only k-tiles with |q - k| < ~450 matter
    int ktLo = 0, ktHi = 16;
    if (branch == 0) {
        ktLo = qt * 2 - 7; if (ktLo < 0) ktLo = 0;
        ktHi = qt * 2 + 9; if (ktHi > 16) ktHi = 16;
    }

    // ---- Q B-operand fragments straight from global ----
    bf16x8 aQ[2][2];
#pragma unroll
    for (int qg = 0; qg < 2; ++qg)
#pragma unroll
        for (int kh = 0; kh < 2; ++kh)
            aQ[qg][kh] = *(const bf16x8*)&Qg[
                (size_t)(qbase + w * 32 + qg * 16 + lc) * 64 + kh * 32 + lr4 * 8];

    auto stage = [&](int kt, int buf) {
#pragma unroll
        for (int i = 0; i < 4; i++) {
            int id = w * 4 + i;
            int kh = (id >> 2) & 1, ch = id & 3;
            if (id < 8)
                async16(Kg + (size_t)(kt * 64 + ch * 16 + sl) * 64 + kh * 32 + sc,
                        &Kt[buf][kh][ch * 16][0]);
            else
                async16(Vg + (size_t)(ch * 16 + sl) * 1024 + kt * 64 + kh * 32 + sc,
                        &Vt[buf][kh][ch * 16][0]);
        }
    };

    stage(ktLo, 0);
    __syncthreads();

    const float C2 = (1.0f - decayf[0]) * 1.44269504f;
    const float qf = (float)(qbase + w * 32 + lc);

    float lrun[2] = {0.f, 0.f};
    f32x4 o[2][4];
#pragma unroll
    for (int qg = 0; qg < 2; ++qg)
#pragma unroll
        for (int dt = 0; dt < 4; ++dt) o[qg][dt] = (f32x4){0.f, 0.f, 0.f, 0.f};

    for (int kt = ktLo, it = 0; kt < ktHi; ++kt, ++it) {
        const int cur = it & 1;
        if (kt + 1 < ktHi) stage(kt + 1, cur ^ 1);

        bf16x8 ak[4][2];
#pragma unroll
        for (int nt = 0; nt < 4; ++nt) {
            ak[nt][0] = *(const bf16x8*)&Kt[cur][0][nt * 16 + lc][lr4 * 8];
            ak[nt][1] = *(const bf16x8*)&Kt[cur][1][nt * 16 + lc][lr4 * 8];
        }

#pragma unroll
        for (int qg = 0; qg < 2; ++qg) {
            f32x4 s[4];
#pragma unroll
            for (int nt = 0; nt < 4; ++nt) {
                s[nt] = (f32x4){0.f, 0.f, 0.f, 0.f};
                s[nt] = MFMA_BF16(ak[nt][0], aQ[qg][0], s[nt]);
                s[nt] = MFMA_BF16(ak[nt][1], aQ[qg][1], s[nt]);
            }
            const float d0 = qf + (float)(qg * 16 - kt * 64 - lr4 * 4);
            float sum = 0.f;
#pragma unroll
            for (int nt = 0; nt < 4; ++nt) {
                float p[4];
#pragma unroll
                for (int r = 0; r < 4; ++r) {
                    float a = s[nt][r];
                    if (branch == 0)
                        a -= fabsf(d0 - (float)(nt * 16 + r)) * C2;
                    p[r] = __builtin_amdgcn_exp2f(a);
                    sum += p[r];
                }
                uint2 w2 = {pack2(p[0], p[1]), pack2(p[2], p[3])};
                *(uint2*)&Ps[w][qg * 16 + lc][nt * 16 + lr4 * 4] = w2;
            }
            lrun[qg] += sum;
        }

        bf16x8 pb[2][2];
#pragma unroll
        for (int qg = 0; qg < 2; ++qg)
#pragma unroll
            for (int c = 0; c < 2; ++c)
                pb[qg][c] = *(const bf16x8*)&Ps[w][qg * 16 + lc][c * 32 + lr4 * 8];
#pragma unroll
        for (int dt = 0; dt < 4; ++dt) {
            bf16x8 v0 = *(const bf16x8*)&Vt[cur][0][dt * 16 + lc][lr4 * 8];
            bf16x8 v1 = *(const bf16x8*)&Vt[cur][1][dt * 16 + lc][lr4 * 8];
#pragma unroll
            for (int qg = 0; qg < 2; ++qg) {
                o[qg][dt] = MFMA_BF16(v0, pb[qg][0], o[qg][dt]);
                o[qg][dt] = MFMA_BF16(v1, pb[qg][1], o[qg][dt]);
            }
        }

        __syncthreads();
    }

#pragma unroll
    for (int qg = 0; qg < 2; ++qg) {
        float s = lrun[qg];
        s += __shfl_xor(s, 16);
        s += __shfl_xor(s, 32);
        float inv = 1.0f / s;
        int qrow = qbase + w * 32 + qg * 16 + lc;
        u16* op = outp + ((size_t)(b * 1024) + qrow) * 1024 + h * 64;
#pragma unroll
        for (int dt = 0; dt < 4; ++dt) {
            uint2 w2 = {pack2(o[qg][dt][0] * inv, o[qg][dt][1] * inv),
                        pack2(o[qg][dt][2] * inv, o[qg][dt][3] * inv)};
            *(uint2*)&op[dt * 16 + lr4 * 4] = w2;
        }
    }
}

// ---------------------------------------------------------------------------
// Mix: attn = alpha*Os + (1-alpha)*Ol, elementwise bf16.
// ---------------------------------------------------------------------------
__global__ __launch_bounds__(256) void mix_kernel(
    const u16* __restrict__ Os, const u16* __restrict__ Ol,
    const float* __restrict__ mixw, u16* __restrict__ dst)
{
    const float a = 1.0f / (1.0f + __expf(-mixw[0]));
    int i = blockIdx.x * 256 + threadIdx.x;
    uint4 s = ((const uint4*)Os)[i];
    uint4 l = ((const uint4*)Ol)[i];
    unsigned su[4] = {s.x, s.y, s.z, s.w};
    unsigned lu[4] = {l.x, l.y, l.z, l.w};
    unsigned ou[4];
#pragma unroll
    for (int k = 0; k < 4; ++k) {
        float s0 = bf2f((u16)su[k]), s1 = bf2f((u16)(su[k] >> 16));
        float l0 = bf2f((u16)lu[k]), l1 = bf2f((u16)(lu[k] >> 16));
        ou[k] = pack2(l0 + a * (s0 - l0), l1 + a * (s1 - l1));
    }
    ((uint4*)dst)[i] = make_uint4(ou[0], ou[1], ou[2], ou[3]);
}

// ---------------------------------------------------------------------------
extern "C" void kernel_launch(void* const* d_in, const int* in_sizes, int n_in,
                              void* d_out, int out_size, void* d_ws, size_t ws_size,
                              hipStream_t stream) {
    const float* x      = (const float*)d_in[0];
    const float* Wq     = (const float*)d_in[1];
    const float* Wkvs   = (const float*)d_in[2];
    const float* Wkvl   = (const float*)d_in[3];
    const float* Wo     = (const float*)d_in[4];
    const float* mixw   = (const float*)d_in[5];
    const float* decayf = (const float*)d_in[6];

    const size_t M1 = 1024 * 1024;
    u16* ws    = (u16*)d_ws;
    u16* xb    = ws;               // 4M  (reused as Os after gemm_proj)
    u16* wqt   = xb + 4 * M1;      // 1M  (wqt..wkvlt reused as Ol)
    u16* wkvst = wqt + 1 * M1;     // 2M
    u16* wkvlt = wkvst + 2 * M1;   // 2M
    u16* wot   = wkvlt + 2 * M1;   // 1M
    u16* qb    = wot + 1 * M1;     // 4M
    u16* ksb   = qb + 4 * M1;      // 4M
    u16* vsb   = ksb + 4 * M1;     // 4M  ([B,16,64,L])
    u16* klb   = vsb + 4 * M1;     // 4M
    u16* vlb   = klb + 4 * M1;     // 4M
    u16* attnb = vlb + 4 * M1;     // 4M
    u16* osb   = xb;               // alias: free after gemm_proj
    u16* olb   = wqt;              // alias: free after gemm_proj

    cvt_x<<<4096, 256, 0, stream>>>(x, xb);
    cvt_w_all<<<dim3(192, 32), 256, 0, stream>>>(Wq, Wkvs, Wkvl, Wo,
                                                 wqt, wkvst, wkvlt, wot);
    gemm_proj<<<dim3(40, 32), 256, 0, stream>>>(xb, wqt, wkvst, wkvlt,
                                                qb, ksb, vsb, klb, vlb);
    attn_mfma<<<dim3(16, 8, 8), 256, 0, stream>>>(qb, ksb, vsb, klb, vlb,
                                                  decayf, osb, olb);
    mix_kernel<<<2048, 256, 0, stream>>>(osb, olb, mixw, attnb);
    gemm_out<<<dim3(8, 64), 256, 0, stream>>>(attnb, wot, (float*)d_out);
}